// Round 2
// baseline (445.306 us; speedup 1.0000x reference)
//
#include <hip/hip_runtime.h>
#include <math.h>

// CausalSelfAttention w/ KV cache, MI355X gfx950.
// B=8 T=64 C=2048 H=16 hd=128 S=4096 -> SKV=4160. All device I/O is FLOAT32.
// Internals: bf16 MFMA (16x16x32), f32 accumulate. Pipeline:
//  [gemm qkv -> q_ws(bf16,scaled) + k/v tails(f32)] ->
//  [fused cache-copy + flash-attn, 5-way key split, partials in ws] ->
//  [combine -> yhead(f32)] -> [gemm proj -> y(f32)].

typedef __attribute__((ext_vector_type(4))) float f32x4;
typedef __attribute__((ext_vector_type(8))) short s16x8;
typedef __attribute__((ext_vector_type(4))) unsigned int u32x4;

#define MFMA_BF16(A_, B_, C_) __builtin_amdgcn_mfma_f32_16x16x32_bf16((A_), (B_), (C_), 0, 0, 0)

__device__ __forceinline__ unsigned short f2bf(float f) {
  unsigned int u = __builtin_bit_cast(unsigned int, f);
  u += 0x7FFFu + ((u >> 16) & 1u);
  return (unsigned short)(u >> 16);
}
__device__ __forceinline__ unsigned int pack2(float a, float b) {
  return (unsigned int)f2bf(a) | ((unsigned int)f2bf(b) << 16);
}

// ---------------------------------------------------------------------------
// GEMM: C[m][n] = sum_k A[m][k] * W[k][n].  M=512, K=2048, N=ncols. A,W f32.
// mode 0 (qkv, ncols=6144): n<2048 -> qws (bf16, *QSCALE, [B,H,T,hd]);
//   2048..4095 -> kout tail rows 4096..4159 (f32); >=4096 -> vout tail (f32).
// mode 1 (proj, ncols=2048): store f32 to yout[512][2048].
// ---------------------------------------------------------------------------
constexpr int LDTg = 72; // bf16 row stride 144B (16B-aligned)
constexpr float QSCALE = 0.08838834764831845f * 1.4426950408889634f; // 1/sqrt(128)*log2e

__global__ __launch_bounds__(256) void gemm_kernel(
    const float* __restrict__ A, const float* __restrict__ W,
    int ncols, int mode,
    unsigned short* __restrict__ qws, float* __restrict__ kout,
    float* __restrict__ vout, float* __restrict__ yout)
{
  __shared__ __align__(16) unsigned short Alds[128][LDTg];
  __shared__ __align__(16) unsigned short Blds[128][LDTg]; // [n][k], k chunk-XOR swizzled

  const int tid = threadIdx.x;
  const int w = tid >> 6, l = tid & 63;
  const int lr = l & 15, lg = l >> 4;
  const int m0 = blockIdx.x * 128;
  const int n0 = blockIdx.y * 128;
  const int wm = (w >> 1) * 64, wn = (w & 1) * 64;

  const int arow = tid >> 3, acol = (tid & 7) << 3;
  const int brow = tid >> 4, bcol = (tid & 15) << 3;
  const int bswz = ((bcol >> 3) & 7) << 3;

  f32x4 acc[4][4] = {};

  for (int ks = 0; ks < 2048 / 64; ++ks) {
    const int k0 = ks * 64;
#pragma unroll
    for (int i = 0; i < 4; ++i) {
      const int r = i * 32 + arow;
      const float* pa = A + (size_t)(m0 + r) * 2048 + k0 + acol;
      const f32x4 a0 = *(const f32x4*)pa;
      const f32x4 a1 = *(const f32x4*)(pa + 4);
      u32x4 p;
      p[0] = pack2(a0[0], a0[1]); p[1] = pack2(a0[2], a0[3]);
      p[2] = pack2(a1[0], a1[1]); p[3] = pack2(a1[2], a1[3]);
      *(u32x4*)(&Alds[r][acol]) = p;
    }
#pragma unroll
    for (int i = 0; i < 4; ++i) {
      const int kr = i * 16 + brow;
      const float* pw = W + (size_t)(k0 + kr) * ncols + n0 + bcol;
      const f32x4 b0 = *(const f32x4*)pw;
      const f32x4 b1 = *(const f32x4*)(pw + 4);
      const int kc = kr ^ bswz;
      Blds[bcol + 0][kc] = f2bf(b0[0]); Blds[bcol + 1][kc] = f2bf(b0[1]);
      Blds[bcol + 2][kc] = f2bf(b0[2]); Blds[bcol + 3][kc] = f2bf(b0[3]);
      Blds[bcol + 4][kc] = f2bf(b1[0]); Blds[bcol + 5][kc] = f2bf(b1[1]);
      Blds[bcol + 6][kc] = f2bf(b1[2]); Blds[bcol + 7][kc] = f2bf(b1[3]);
    }
    __syncthreads();

    s16x8 af[4][2], bfr[4][2];
#pragma unroll
    for (int mi = 0; mi < 4; ++mi)
#pragma unroll
      for (int kk = 0; kk < 2; ++kk)
        af[mi][kk] = *(const s16x8*)(&Alds[wm + mi * 16 + lr][kk * 32 + lg * 8]);
#pragma unroll
    for (int ni = 0; ni < 4; ++ni) {
      const int n = wn + ni * 16 + lr;
      const int nswz = ((n >> 3) & 7) << 3;
#pragma unroll
      for (int kk = 0; kk < 2; ++kk)
        bfr[ni][kk] = *(const s16x8*)(&Blds[n][(kk * 32 + lg * 8) ^ nswz]);
    }
#pragma unroll
    for (int kk = 0; kk < 2; ++kk)
#pragma unroll
      for (int mi = 0; mi < 4; ++mi)
#pragma unroll
        for (int ni = 0; ni < 4; ++ni)
          acc[mi][ni] = MFMA_BF16(af[mi][kk], bfr[ni][kk], acc[mi][ni]);
    __syncthreads();
  }

  if (mode == 0) {
    const int which = n0 >> 11;          // 0=q 1=k 2=v (BN=128 == one head)
    const int h = (n0 >> 7) & 15;
    float* kv = (which == 1) ? kout : vout;
#pragma unroll
    for (int mi = 0; mi < 4; ++mi)
#pragma unroll
      for (int ni = 0; ni < 4; ++ni) {
        const int d = wn + ni * 16 + lr;
#pragma unroll
        for (int r = 0; r < 4; ++r) {
          const int mg = m0 + wm + mi * 16 + lg * 4 + r;
          const int b = mg >> 6, t = mg & 63;
          const float val = acc[mi][ni][r];
          if (which == 0)
            qws[(((size_t)(b * 16 + h) * 64 + t) << 7) + d] = f2bf(val * QSCALE);
          else
            kv[((size_t)(b * 16 + h) * 4160 + 4096 + t) * 128 + d] = val;
        }
      }
  } else {
#pragma unroll
    for (int mi = 0; mi < 4; ++mi)
#pragma unroll
      for (int ni = 0; ni < 4; ++ni) {
        const int n = n0 + wn + ni * 16 + lr;
#pragma unroll
        for (int r = 0; r < 4; ++r) {
          const int mg = m0 + wm + mi * 16 + lg * 4 + r;
          yout[(size_t)mg * 2048 + n] = acc[mi][ni][r];
        }
      }
  }
}

// ---------------------------------------------------------------------------
// Fused KV-cache copy + flash attention (partial, per key segment).
// Block = (bh, seg): 4 waves, wave w owns queries w*16..w*16+15.
// Per 32-key tile: f32x4-stage K/V from past (exact-bit copy to kout/vout) or
// read tail from kout/vout; convert to bf16 into LDS; S=QK^T MFMA; online
// softmax (exp2, scale folded into q); P->LDS->A-frag; PV MFMA with
// XOR-swizzled V^T. Writes unnormalized O (f32) and (m,l) to ws.
// ---------------------------------------------------------------------------
__global__ __launch_bounds__(256) void attn_kernel(
    const float* __restrict__ pastk, const float* __restrict__ pastv,
    const unsigned short* __restrict__ qws,
    float* __restrict__ kout, float* __restrict__ vout,
    float* __restrict__ Ows, float* __restrict__ mlws,
    int nseg, int seglen, int ntiles)
{
  __shared__ __align__(16) unsigned short Klds[32][136]; // +8 pad
  __shared__ __align__(16) unsigned short VT[128][32];   // [d][k ^ ((d>>3)&3)<<3]
  __shared__ __align__(16) unsigned short Plds[4][16][40];

  const int tid = threadIdx.x;
  const int w = tid >> 6, l = tid & 63;
  const int lr = l & 15, lg = l >> 4;
  const int bh = blockIdx.x / nseg;
  const int seg = blockIdx.x % nseg;
  const int segbase = seg * seglen;

  s16x8 qf[4];
  {
    const unsigned short* qb = qws + ((size_t)bh * 64 + w * 16 + lr) * 128 + lg * 8;
#pragma unroll
    for (int kk = 0; kk < 4; ++kk) qf[kk] = *(const s16x8*)(qb + kk * 32);
  }

  float mrow[4] = {-INFINITY, -INFINITY, -INFINITY, -INFINITY};
  float lrowv[4] = {0.f, 0.f, 0.f, 0.f};
  f32x4 Oacc[8] = {};

  const int skr = tid >> 3;          // 0..31: key row in tile
  const int sd0 = (tid & 7) << 4;    // 0..112: 16-float column chunk

  for (int t = 0; t < ntiles; ++t) {
    const int s0 = segbase + t * 32;
    const int s = s0 + skr;
    const size_t ooff = ((size_t)bh * 4160 + s) * 128 + sd0;
    f32x4 kv4[4], vv4[4];
    if (s < 4096) {
      const float* pkp = pastk + ((size_t)bh * 4096 + s) * 128 + sd0;
      const float* pvp = pastv + ((size_t)bh * 4096 + s) * 128 + sd0;
#pragma unroll
      for (int j = 0; j < 4; ++j) { kv4[j] = *(const f32x4*)(pkp + 4 * j); vv4[j] = *(const f32x4*)(pvp + 4 * j); }
#pragma unroll
      for (int j = 0; j < 4; ++j) { *(f32x4*)(kout + ooff + 4 * j) = kv4[j]; *(f32x4*)(vout + ooff + 4 * j) = vv4[j]; }
    } else {
#pragma unroll
      for (int j = 0; j < 4; ++j) { kv4[j] = *(const f32x4*)(kout + ooff + 4 * j); vv4[j] = *(const f32x4*)(vout + ooff + 4 * j); }
    }
    u32x4 p0, p1;
    p0[0] = pack2(kv4[0][0], kv4[0][1]); p0[1] = pack2(kv4[0][2], kv4[0][3]);
    p0[2] = pack2(kv4[1][0], kv4[1][1]); p0[3] = pack2(kv4[1][2], kv4[1][3]);
    p1[0] = pack2(kv4[2][0], kv4[2][1]); p1[1] = pack2(kv4[2][2], kv4[2][3]);
    p1[2] = pack2(kv4[3][0], kv4[3][1]); p1[3] = pack2(kv4[3][2], kv4[3][3]);
    *(u32x4*)(&Klds[skr][sd0]) = p0;
    *(u32x4*)(&Klds[skr][sd0 + 8]) = p1;
#pragma unroll
    for (int jj = 0; jj < 16; ++jj) {
      const int d = sd0 + jj;
      VT[d][skr ^ (((d >> 3) & 3) << 3)] = f2bf(vv4[jj >> 2][jj & 3]);
    }
    __syncthreads();

    f32x4 sc[2] = {};
#pragma unroll
    for (int kk = 0; kk < 4; ++kk)
#pragma unroll
      for (int st = 0; st < 2; ++st) {
        s16x8 kf = *(const s16x8*)(&Klds[st * 16 + lr][kk * 32 + lg * 8]);
        sc[st] = MFMA_BF16(qf[kk], kf, sc[st]);
      }

#pragma unroll
    for (int r = 0; r < 4; ++r) {
      float tm = fmaxf(sc[0][r], sc[1][r]);
      tm = fmaxf(tm, __shfl_xor(tm, 1));
      tm = fmaxf(tm, __shfl_xor(tm, 2));
      tm = fmaxf(tm, __shfl_xor(tm, 4));
      tm = fmaxf(tm, __shfl_xor(tm, 8));
      const float mn = fmaxf(mrow[r], tm);
      const float alpha = exp2f(mrow[r] - mn);
      mrow[r] = mn;
      const float p0f = exp2f(sc[0][r] - mn);
      const float p1f = exp2f(sc[1][r] - mn);
      float rs = p0f + p1f;
      rs += __shfl_xor(rs, 1);
      rs += __shfl_xor(rs, 2);
      rs += __shfl_xor(rs, 4);
      rs += __shfl_xor(rs, 8);
      lrowv[r] = lrowv[r] * alpha + rs;
#pragma unroll
      for (int dt = 0; dt < 8; ++dt) Oacc[dt][r] *= alpha;
      Plds[w][lg * 4 + r][lr] = f2bf(p0f);
      Plds[w][lg * 4 + r][16 + lr] = f2bf(p1f);
    }

    s16x8 pf = *(const s16x8*)(&Plds[w][lr][lg * 8]);
#pragma unroll
    for (int dt = 0; dt < 8; ++dt) {
      const int d = dt * 16 + lr;
      s16x8 vf = *(const s16x8*)(&VT[d][(lg * 8) ^ (((d >> 3) & 3) << 3)]);
      Oacc[dt] = MFMA_BF16(pf, vf, Oacc[dt]);
    }
    __syncthreads();
  }

  const size_t rowbase = ((size_t)seg * 128 + bh) * 64 + w * 16;
#pragma unroll
  for (int dt = 0; dt < 8; ++dt)
#pragma unroll
    for (int r = 0; r < 4; ++r)
      Ows[(rowbase + lg * 4 + r) * 128 + dt * 16 + lr] = Oacc[dt][r];
  if (lr == 0) {
#pragma unroll
    for (int r = 0; r < 4; ++r) {
      const size_t mi = rowbase + lg * 4 + r;
      mlws[mi * 2 + 0] = mrow[r];
      mlws[mi * 2 + 1] = lrowv[r];
    }
  }
}

// ---------------------------------------------------------------------------
// Merge nseg partials -> yhead[(b*64+q)][h*128+d] (f32 [512][2048]).
// ---------------------------------------------------------------------------
__global__ __launch_bounds__(256) void combine_kernel(
    const float* __restrict__ Ows, const float* __restrict__ mlws,
    float* __restrict__ yhead, int nseg)
{
  const int idx = blockIdx.x * 256 + threadIdx.x;
  const int d = idx & 127;
  const int row = idx >> 7;            // bh*64+q, 0..8191
  float M = -INFINITY;
  for (int s = 0; s < nseg; ++s) M = fmaxf(M, mlws[((size_t)s * 8192 + row) * 2]);
  float num = 0.f, den = 0.f;
  for (int s = 0; s < nseg; ++s) {
    const size_t r = (size_t)s * 8192 + row;
    const float wgt = exp2f(mlws[r * 2] - M);
    den += wgt * mlws[r * 2 + 1];
    num += wgt * Ows[r * 128 + d];
  }
  const float o = num / den;
  const int bh = row >> 6, q = row & 63;
  const int b = bh >> 4, h = bh & 15;
  yhead[(size_t)(b * 64 + q) * 2048 + h * 128 + d] = o;
}

// ---------------------------------------------------------------------------
extern "C" void kernel_launch(void* const* d_in, const int* in_sizes, int n_in,
                              void* d_out, int out_size, void* d_ws, size_t ws_size,
                              hipStream_t stream)
{
  (void)in_sizes; (void)n_in; (void)out_size;
  const float* x  = (const float*)d_in[0];
  const float* pk = (const float*)d_in[1];
  const float* pv = (const float*)d_in[2];
  const float* wa = (const float*)d_in[3];
  const float* wp = (const float*)d_in[4];

  float* out  = (float*)d_out;
  float* y    = out;                          // 1,048,576
  float* kout = out + 1048576;                // 68,157,440
  float* vout = out + 1048576 + 68157440;     // 68,157,440

  char* ws = (char*)d_ws;
  unsigned short* qws = (unsigned short*)(ws);                      // 2 MiB bf16
  float* yhead = (float*)(ws + ((size_t)2 << 20));                  // 4 MiB f32
  float* mlws  = (float*)(ws + ((size_t)6 << 20));                  // <=320 KiB
  float* Ows   = (float*)(ws + ((size_t)7 << 20));                  // nseg*4 MiB

  const size_t base = (size_t)7 << 20;
  int nseg = 1;
  if (ws_size >= base + (size_t)5 * 4194304) nseg = 5;       // 640 blocks, 2.5/CU
  else if (ws_size >= base + (size_t)2 * 4194304) nseg = 2;
  const int seglen = 4160 / nseg;   // 832 / 2080 / 4160 (multiples of 32)
  const int ntiles = seglen / 32;

  gemm_kernel<<<dim3(4, 48), dim3(256), 0, stream>>>(x, wa, 6144, 0, qws, kout, vout, nullptr);
  attn_kernel<<<dim3(128 * nseg), dim3(256), 0, stream>>>(pk, pv, qws, kout, vout, Ows, mlws,
                                                          nseg, seglen, ntiles);
  combine_kernel<<<dim3(4096), dim3(256), 0, stream>>>(Ows, mlws, yhead, nseg);
  gemm_kernel<<<dim3(4, 16), dim3(256), 0, stream>>>(yhead, wp, 2048, 1, nullptr, nullptr, nullptr, y);
}

// Round 3
// 374.130 us; speedup vs baseline: 1.1902x; 1.1902x over previous
//
#include <hip/hip_runtime.h>
#include <math.h>

// CausalSelfAttention w/ KV cache, MI355X gfx950.
// B=8 T=64 C=2048 H=16 hd=128 S=4096 -> SKV=4160. All device I/O is FLOAT32.
// Internals: bf16 MFMA (16x16x32), f32 accumulate.
// R3 changes: attn staging interleaved-coalesced + store-after-barrier +
// register prefetch of next tile; nseg 5->10; gemm k-step register prefetch +
// paired-k b32 B-staging; proj BM=64 (128 blocks).

typedef __attribute__((ext_vector_type(4))) float f32x4;
typedef __attribute__((ext_vector_type(8))) short s16x8;
typedef __attribute__((ext_vector_type(2))) unsigned int u32x2;
typedef __attribute__((ext_vector_type(4))) unsigned int u32x4;

#define MFMA_BF16(A_, B_, C_) __builtin_amdgcn_mfma_f32_16x16x32_bf16((A_), (B_), (C_), 0, 0, 0)

__device__ __forceinline__ unsigned short f2bf(float f) {
  unsigned int u = __builtin_bit_cast(unsigned int, f);
  u += 0x7FFFu + ((u >> 16) & 1u);
  return (unsigned short)(u >> 16);
}
__device__ __forceinline__ unsigned int pack2(float a, float b) {
  return (unsigned int)f2bf(a) | ((unsigned int)f2bf(b) << 16);
}

// ---------------------------------------------------------------------------
// GEMM: C[m][n] = sum_k A[m][k]*W[k][n]. M=512, K=2048, N=ncols. A,W f32.
// BM x 128 tile, 4 waves (2x2), register-prefetched k-steps of 64.
// mode 0 (qkv, BM=128, ncols=6144): n<2048 -> qws (bf16 * QSCALE, [B,H,T,hd]);
//   2048..4095 -> kout tail rows 4096..4159 (f32); >=4096 -> vout tail (f32).
// mode 1 (proj, BM=64, ncols=2048): f32 store to yout[512][2048].
// ---------------------------------------------------------------------------
constexpr float QSCALE = 0.08838834764831845f * 1.4426950408889634f; // 1/sqrt(128)*log2e

template <int BM>
__global__ __launch_bounds__(256) void gemm_kernel(
    const float* __restrict__ A, const float* __restrict__ W,
    int ncols, int mode,
    unsigned short* __restrict__ qws, float* __restrict__ kout,
    float* __restrict__ vout, float* __restrict__ yout)
{
  constexpr int MI = BM / 32;          // m-frags per wave
  constexpr int AIT = BM / 32;         // A staging iters (32 rows each)
  __shared__ __align__(16) unsigned short Alds[BM][72];
  __shared__ __align__(16) unsigned short Blds[128][72]; // [n][k], k chunk-XOR swizzled

  const int tid = threadIdx.x;
  const int w = tid >> 6, l = tid & 63;
  const int lr = l & 15, lg = l >> 4;
  const int m0 = blockIdx.x * BM;
  const int n0 = blockIdx.y * 128;
  const int wm = (w >> 1) * (BM / 2), wn = (w & 1) * 64;

  const int arow = tid >> 3, acol = (tid & 7) << 3;
  const int bkp = tid >> 4, bcol = (tid & 15) << 3;
  const int bswz = ((bcol >> 3) & 7) << 3;

  f32x4 ar[AIT][2];
  f32x4 br[2][4];

  auto loadA = [&](int k0) {
#pragma unroll
    for (int it = 0; it < AIT; ++it) {
      const float* pa = A + (size_t)(m0 + it * 32 + arow) * 2048 + k0 + acol;
      ar[it][0] = *(const f32x4*)pa;
      ar[it][1] = *(const f32x4*)(pa + 4);
    }
  };
  auto loadB = [&](int k0) {
#pragma unroll
    for (int i = 0; i < 2; ++i) {
      const int krow = 2 * (i * 16 + bkp);
      const float* pw = W + (size_t)(k0 + krow) * ncols + n0 + bcol;
      br[i][0] = *(const f32x4*)pw;
      br[i][1] = *(const f32x4*)(pw + 4);
      br[i][2] = *(const f32x4*)(pw + ncols);
      br[i][3] = *(const f32x4*)(pw + ncols + 4);
    }
  };

  f32x4 acc[MI][4] = {};

  loadA(0); loadB(0);
  for (int ks = 0; ks < 32; ++ks) {
    // regs -> LDS (bf16)
#pragma unroll
    for (int it = 0; it < AIT; ++it) {
      u32x4 p;
      p[0] = pack2(ar[it][0][0], ar[it][0][1]); p[1] = pack2(ar[it][0][2], ar[it][0][3]);
      p[2] = pack2(ar[it][1][0], ar[it][1][1]); p[3] = pack2(ar[it][1][2], ar[it][1][3]);
      *(u32x4*)(&Alds[it * 32 + arow][acol]) = p;
    }
#pragma unroll
    for (int i = 0; i < 2; ++i) {
      const int krow = 2 * (i * 16 + bkp);
      const int kc = krow ^ bswz;   // bswz touches bits>=3 only: kc,kc+1 adjacent
#pragma unroll
      for (int j = 0; j < 8; ++j) {
        const float v0 = (j < 4) ? br[i][0][j] : br[i][1][j - 4];
        const float v1 = (j < 4) ? br[i][2][j] : br[i][3][j - 4];
        *(unsigned int*)(&Blds[bcol + j][kc]) = pack2(v0, v1);
      }
    }
    __syncthreads();

    if (ks < 31) { loadA((ks + 1) * 64); loadB((ks + 1) * 64); } // overlap w/ MFMA

    s16x8 af[MI][2], bfr[4][2];
#pragma unroll
    for (int mi = 0; mi < MI; ++mi)
#pragma unroll
      for (int kk = 0; kk < 2; ++kk)
        af[mi][kk] = *(const s16x8*)(&Alds[wm + mi * 16 + lr][kk * 32 + lg * 8]);
#pragma unroll
    for (int ni = 0; ni < 4; ++ni) {
      const int n = wn + ni * 16 + lr;
      const int nswz = ((n >> 3) & 7) << 3;
#pragma unroll
      for (int kk = 0; kk < 2; ++kk)
        bfr[ni][kk] = *(const s16x8*)(&Blds[n][(kk * 32 + lg * 8) ^ nswz]);
    }
#pragma unroll
    for (int kk = 0; kk < 2; ++kk)
#pragma unroll
      for (int mi = 0; mi < MI; ++mi)
#pragma unroll
        for (int ni = 0; ni < 4; ++ni)
          acc[mi][ni] = MFMA_BF16(af[mi][kk], bfr[ni][kk], acc[mi][ni]);
    __syncthreads();
  }

  if (mode == 0) {
    const int which = n0 >> 11;          // 0=q 1=k 2=v (BN=128 == one head)
    const int h = (n0 >> 7) & 15;
    float* kv = (which == 1) ? kout : vout;
#pragma unroll
    for (int mi = 0; mi < MI; ++mi)
#pragma unroll
      for (int ni = 0; ni < 4; ++ni) {
        const int d = wn + ni * 16 + lr;
#pragma unroll
        for (int r = 0; r < 4; ++r) {
          const int mg = m0 + wm + mi * 16 + lg * 4 + r;
          const int b = mg >> 6, t = mg & 63;
          const float val = acc[mi][ni][r];
          if (which == 0)
            qws[(((size_t)(b * 16 + h) * 64 + t) << 7) + d] = f2bf(val * QSCALE);
          else
            kv[((size_t)(b * 16 + h) * 4160 + 4096 + t) * 128 + d] = val;
        }
      }
  } else {
#pragma unroll
    for (int mi = 0; mi < MI; ++mi)
#pragma unroll
      for (int ni = 0; ni < 4; ++ni) {
        const int n = n0 + wn + ni * 16 + lr;
#pragma unroll
        for (int r = 0; r < 4; ++r) {
          const int mg = m0 + wm + mi * 16 + lg * 4 + r;
          yout[(size_t)mg * 2048 + n] = acc[mi][ni][r];
        }
      }
  }
}

// ---------------------------------------------------------------------------
// Fused KV-cache copy + flash attention (partial, per key segment).
// Block = (bh, seg): 4 waves, wave w owns queries w*16..w*16+15.
// Per 32-key tile: coalesced f32x4 loads (interleaved lanes), convert->LDS,
// barrier, THEN cache-copy stores + next-tile register prefetch (both overlap
// the MFMA/softmax compute), compute, barrier.
// ---------------------------------------------------------------------------
__global__ __launch_bounds__(256) void attn_kernel(
    const float* __restrict__ pastk, const float* __restrict__ pastv,
    const unsigned short* __restrict__ qws,
    float* __restrict__ kout, float* __restrict__ vout,
    float* __restrict__ Ows, float* __restrict__ mlws,
    int nseg, int seglen, int ntiles)
{
  __shared__ __align__(16) unsigned short Klds[32][136]; // +8 pad
  __shared__ __align__(16) unsigned short VT[128][32];   // [d][k ^ ((d>>3)&3)<<3]
  __shared__ __align__(16) unsigned short Plds[4][16][40];

  const int tid = threadIdx.x;
  const int w = tid >> 6, l = tid & 63;
  const int lr = l & 15, lg = l >> 4;
  const int bh = blockIdx.x / nseg;
  const int seg = blockIdx.x % nseg;
  const int segbase = seg * seglen;

  s16x8 qf[4];
  {
    const unsigned short* qb = qws + ((size_t)bh * 64 + w * 16 + lr) * 128 + lg * 8;
#pragma unroll
    for (int kk = 0; kk < 4; ++kk) qf[kk] = *(const s16x8*)(qb + kk * 32);
  }

  float mrow[4] = {-INFINITY, -INFINITY, -INFINITY, -INFINITY};
  float lrowv[4] = {0.f, 0.f, 0.f, 0.f};
  f32x4 Oacc[8] = {};

  const int skr = tid >> 3;        // key row in tile (0..31)
  const int sd = (tid & 7) << 2;   // interleaved: lane covers floats sd+32c+{0..3}

  f32x4 kv[4], vv[4];
  int scur = 0; size_t oocur = 0;

  auto load_tile = [&](int t) {
    const int s = segbase + t * 32 + skr;
    const size_t oo = ((size_t)bh * 4160 + s) * 128 + sd;
    scur = s; oocur = oo;
    if (s < 4096) {
      const float* a = pastk + ((size_t)bh * 4096 + s) * 128 + sd;
      const float* b = pastv + ((size_t)bh * 4096 + s) * 128 + sd;
#pragma unroll
      for (int c = 0; c < 4; ++c) { kv[c] = *(const f32x4*)(a + 32 * c); vv[c] = *(const f32x4*)(b + 32 * c); }
    } else {
#pragma unroll
      for (int c = 0; c < 4; ++c) { kv[c] = *(const f32x4*)(kout + oo + 32 * c); vv[c] = *(const f32x4*)(vout + oo + 32 * c); }
    }
  };

  load_tile(0);
  for (int t = 0; t < ntiles; ++t) {
    // convert regs -> LDS
#pragma unroll
    for (int c = 0; c < 4; ++c) {
      const int d0 = sd + 32 * c;
      u32x2 pk;
      pk[0] = pack2(kv[c][0], kv[c][1]);
      pk[1] = pack2(kv[c][2], kv[c][3]);
      *(u32x2*)(&Klds[skr][d0]) = pk;
#pragma unroll
      for (int e = 0; e < 4; ++e) {
        const int d = d0 + e;
        VT[d][skr ^ (((d >> 3) & 3) << 3)] = f2bf(vv[c][e]);
      }
    }
    const bool dostore = (scur < 4096);
    const size_t oost = oocur;
    __syncthreads();

    if (dostore) {       // cache-copy: overlaps compute below
      float* ko = kout + oost; float* vo = vout + oost;
#pragma unroll
      for (int c = 0; c < 4; ++c) { *(f32x4*)(ko + 32 * c) = kv[c]; *(f32x4*)(vo + 32 * c) = vv[c]; }
    }
    if (t + 1 < ntiles) load_tile(t + 1);   // prefetch: overlaps compute below

    f32x4 sc[2] = {};
#pragma unroll
    for (int kk = 0; kk < 4; ++kk)
#pragma unroll
      for (int st = 0; st < 2; ++st) {
        s16x8 kf = *(const s16x8*)(&Klds[st * 16 + lr][kk * 32 + lg * 8]);
        sc[st] = MFMA_BF16(qf[kk], kf, sc[st]);
      }

#pragma unroll
    for (int r = 0; r < 4; ++r) {
      float tm = fmaxf(sc[0][r], sc[1][r]);
      tm = fmaxf(tm, __shfl_xor(tm, 1));
      tm = fmaxf(tm, __shfl_xor(tm, 2));
      tm = fmaxf(tm, __shfl_xor(tm, 4));
      tm = fmaxf(tm, __shfl_xor(tm, 8));
      const float mn = fmaxf(mrow[r], tm);
      const float alpha = exp2f(mrow[r] - mn);
      mrow[r] = mn;
      const float p0f = exp2f(sc[0][r] - mn);
      const float p1f = exp2f(sc[1][r] - mn);
      float rs = p0f + p1f;
      rs += __shfl_xor(rs, 1);
      rs += __shfl_xor(rs, 2);
      rs += __shfl_xor(rs, 4);
      rs += __shfl_xor(rs, 8);
      lrowv[r] = lrowv[r] * alpha + rs;
#pragma unroll
      for (int dt = 0; dt < 8; ++dt) Oacc[dt][r] *= alpha;
      Plds[w][lg * 4 + r][lr] = f2bf(p0f);
      Plds[w][lg * 4 + r][16 + lr] = f2bf(p1f);
    }

    s16x8 pf = *(const s16x8*)(&Plds[w][lr][lg * 8]);
#pragma unroll
    for (int dt = 0; dt < 8; ++dt) {
      const int d = dt * 16 + lr;
      s16x8 vf = *(const s16x8*)(&VT[d][(lg * 8) ^ (((d >> 3) & 3) << 3)]);
      Oacc[dt] = MFMA_BF16(pf, vf, Oacc[dt]);
    }
    __syncthreads();
  }

  const size_t rowbase = ((size_t)seg * 128 + bh) * 64 + w * 16;
#pragma unroll
  for (int dt = 0; dt < 8; ++dt)
#pragma unroll
    for (int r = 0; r < 4; ++r)
      Ows[(rowbase + lg * 4 + r) * 128 + dt * 16 + lr] = Oacc[dt][r];
  if (lr == 0) {
#pragma unroll
    for (int r = 0; r < 4; ++r) {
      const size_t mi = rowbase + lg * 4 + r;
      mlws[mi * 2 + 0] = mrow[r];
      mlws[mi * 2 + 1] = lrowv[r];
    }
  }
}

// ---------------------------------------------------------------------------
// Merge nseg partials -> yhead[(b*64+q)][h*128+d] (f32 [512][2048]).
// ---------------------------------------------------------------------------
__global__ __launch_bounds__(256) void combine_kernel(
    const float* __restrict__ Ows, const float* __restrict__ mlws,
    float* __restrict__ yhead, int nseg)
{
  const int idx = blockIdx.x * 256 + threadIdx.x;
  const int d = idx & 127;
  const int row = idx >> 7;            // bh*64+q, 0..8191
  float M = -INFINITY;
  for (int s = 0; s < nseg; ++s) M = fmaxf(M, mlws[((size_t)s * 8192 + row) * 2]);
  float num = 0.f, den = 0.f;
  for (int s = 0; s < nseg; ++s) {
    const size_t r = (size_t)s * 8192 + row;
    const float wgt = exp2f(mlws[r * 2] - M);
    den += wgt * mlws[r * 2 + 1];
    num += wgt * Ows[r * 128 + d];
  }
  const float o = num / den;
  const int bh = row >> 6, q = row & 63;
  const int b = bh >> 4, h = bh & 15;
  yhead[(size_t)(b * 64 + q) * 2048 + h * 128 + d] = o;
}

// ---------------------------------------------------------------------------
extern "C" void kernel_launch(void* const* d_in, const int* in_sizes, int n_in,
                              void* d_out, int out_size, void* d_ws, size_t ws_size,
                              hipStream_t stream)
{
  (void)in_sizes; (void)n_in; (void)out_size;
  const float* x  = (const float*)d_in[0];
  const float* pk = (const float*)d_in[1];
  const float* pv = (const float*)d_in[2];
  const float* wa = (const float*)d_in[3];
  const float* wp = (const float*)d_in[4];

  float* out  = (float*)d_out;
  float* y    = out;                          // 1,048,576
  float* kout = out + 1048576;                // 68,157,440
  float* vout = out + 1048576 + 68157440;     // 68,157,440

  char* ws = (char*)d_ws;
  unsigned short* qws = (unsigned short*)(ws);                      // 2 MiB bf16
  float* yhead = (float*)(ws + ((size_t)2 << 20));                  // 4 MiB f32
  float* mlws  = (float*)(ws + ((size_t)6 << 20));                  // <=640 KiB
  float* Ows   = (float*)(ws + ((size_t)7 << 20));                  // nseg*4 MiB

  const size_t base = (size_t)7 << 20;
  int nseg = 1;
  if (ws_size >= base + (size_t)10 * 4194304) nseg = 10;     // 1280 blocks, 5/CU
  else if (ws_size >= base + (size_t)5 * 4194304) nseg = 5;
  else if (ws_size >= base + (size_t)2 * 4194304) nseg = 2;
  const int seglen = 4160 / nseg;   // 416 / 832 / 2080 / 4160 (multiples of 32)
  const int ntiles = seglen / 32;

  gemm_kernel<128><<<dim3(4, 48), dim3(256), 0, stream>>>(x, wa, 6144, 0, qws, kout, vout, nullptr);
  attn_kernel<<<dim3(128 * nseg), dim3(256), 0, stream>>>(pk, pv, qws, kout, vout, Ows, mlws,
                                                          nseg, seglen, ntiles);
  combine_kernel<<<dim3(4096), dim3(256), 0, stream>>>(Ows, mlws, yhead, nseg);
  gemm_kernel<64><<<dim3(8, 16), dim3(256), 0, stream>>>(yhead, wp, 2048, 1, nullptr, nullptr, nullptr, y);
}